// Round 3
// baseline (854.511 us; speedup 1.0000x reference)
//
#include <hip/hip_runtime.h>
#include <cstdint>
#include <cfloat>

#define NN 2048
#define DD 128
#define BATCH 8
#define STR 34          // LDS stride in doubles for 64x32 chunk (pad 2: 16B rows, <=2-way banks)

typedef double d4 __attribute__((ext_vector_type(4)));

// ---------------- K1: fp64 L2-normalize rows ----------------
__global__ __launch_bounds__(256) void k_normalize(const float* __restrict__ x,
                                                   double* __restrict__ normed) {
  const int wave = threadIdx.x >> 6;
  const int lane = threadIdx.x & 63;
  const long long row = (long long)blockIdx.x * 4 + wave;   // 16384 rows
  float2 v = reinterpret_cast<const float2*>(x + row * DD)[lane];
  const double d0 = (double)v.x, d1 = (double)v.y;
  double s = d0 * d0 + d1 * d1;
  #pragma unroll
  for (int m = 32; m >= 1; m >>= 1) s += __shfl_xor(s, m, 64);
  double denom = sqrt(s);
  denom = denom > 1e-12 ? denom : 1e-12;
  double2 o;
  o.x = d0 / denom;
  o.y = d1 / denom;
  reinterpret_cast<double2*>(normed + row * DD)[lane] = o;
}

// ---------------- K2: zero-fill output + diagonal ----------------
__global__ __launch_bounds__(256) void k_zero_diag(float* __restrict__ out) {
  const long long g = (long long)blockIdx.x * 256 + threadIdx.x;  // float4 id
  const long long p0 = g * 4;
  const int c0 = (int)(p0 & (NN - 1));
  const long long r = p0 >> 11;
  const int n = (int)(r & (NN - 1));
  float4 v;
  v.x = (c0 + 0 == n) ? 1.0f : 0.0f;
  v.y = (c0 + 1 == n) ? 1.0f : 0.0f;
  v.z = (c0 + 2 == n) ? 1.0f : 0.0f;
  v.w = (c0 + 3 == n) ? 1.0f : 0.0f;
  reinterpret_cast<float4*>(out)[g] = v;
}

// Sorted-desc top-8 insertion, tie-break by smaller index (matches jax.lax.top_k).
__device__ __forceinline__ void insert8(double (&v)[8], int (&ix)[8], double nv, int nm) {
  const bool better = (nv > v[7]) || (nv == v[7] && nm < ix[7]);
  if (better) {
    v[7] = nv; ix[7] = nm;
    #pragma unroll
    for (int q = 7; q >= 1; --q) {
      const bool sw = (v[q] > v[q - 1]) || (v[q] == v[q - 1] && ix[q] < ix[q - 1]);
      const double va = v[q - 1], vb = v[q];
      const int ia = ix[q - 1], ib = ix[q];
      v[q - 1] = sw ? vb : va;  v[q] = sw ? va : vb;
      ix[q - 1] = sw ? ib : ia; ix[q] = sw ? ia : ib;
    }
  }
}

// ---------------- K3: fp64 MFMA scores + per-split top-8 candidates ----------------
// grid: 2048 blocks = 256 row-tiles (64 rows) x 8 col-splits (256 cols).
__global__ __launch_bounds__(256, 2) void k_scores_topk(const double* __restrict__ normed,
                                                        double* __restrict__ cand_v,
                                                        int* __restrict__ cand_i) {
  __shared__ __align__(16) double At[64 * STR];   // 17,408 B
  __shared__ __align__(16) double Bt[64 * STR];   // 17,408 B

  const int tid = threadIdx.x;
  const int w = tid >> 6;        // wave 0..3
  const int l = tid & 63;
  const int q = l >> 4;          // k-lane group
  const int c16 = l & 15;

  // --- runtime calibration of the f64 MFMA C/D fragment layout ---
  // A/B operand layout (universal for 16x16, 1 elem/lane): A[i][k] in lane k*16+i,
  // B[k][j] in lane k*16+j. Build A[i][0]=i+1, B[0][j]=1 -> D[i][j]=i+1 (probe rows);
  // A[i][0]=1, B[0][j]=j+1 -> D[i][j]=j+1 (probe cols). Exact small ints in fp64.
  const double k0 = (l < 16) ? 1.0 : 0.0;
  d4 zac = {0.0, 0.0, 0.0, 0.0};
  const d4 dprobe_r = __builtin_amdgcn_mfma_f64_16x16x4f64(k0 * (double)(c16 + 1), k0, zac, 0, 0, 0);
  const d4 dprobe_c = __builtin_amdgcn_mfma_f64_16x16x4f64(k0, k0 * (double)(c16 + 1), zac, 0, 0, 0);
  int rowof[4], colof[4];
  #pragma unroll
  for (int r = 0; r < 4; ++r) {
    rowof[r] = (int)dprobe_r[r] - 1;
    colof[r] = (int)dprobe_c[r] - 1;
  }

  const int rowblk = blockIdx.x >> 3;
  const int split = blockIdx.x & 7;
  const long long row0 = (long long)rowblk * 64;
  const int b = (int)(row0 >> 11);
  const int c0 = split * 256;
  const double* Abase = normed + row0 * DD;
  const double* Bbase = normed + ((long long)b * NN + c0) * DD;

  int srow[4], skp[4];
  #pragma unroll
  for (int i = 0; i < 4; ++i) {
    const int p = tid + i * 256;      // double2 index in 64x32 chunk
    srow[i] = p >> 4;
    skp[i] = (p & 15) * 2;
  }

  double tv[4][8]; int ti[4][8];
  #pragma unroll
  for (int bb = 0; bb < 4; ++bb)
    #pragma unroll
    for (int s = 0; s < 8; ++s) { tv[bb][s] = -DBL_MAX; ti[bb][s] = 0x7fffffff; }

  double2 pfA[4], pfB[4];
  #pragma unroll
  for (int i = 0; i < 4; ++i) {
    pfA[i] = *reinterpret_cast<const double2*>(Abase + srow[i] * DD + skp[i]);
    pfB[i] = *reinterpret_cast<const double2*>(Bbase + srow[i] * DD + skp[i]);
  }

  for (int ct = 0; ct < 4; ++ct) {           // 64-col tiles within the 256-col strip
    d4 acc[4];
    #pragma unroll
    for (int t = 0; t < 4; ++t) acc[t] = (d4){0.0, 0.0, 0.0, 0.0};

    for (int ch = 0; ch < 4; ++ch) {         // K chunks of 32
      __syncthreads();
      #pragma unroll
      for (int i = 0; i < 4; ++i) {
        *reinterpret_cast<double2*>(&At[srow[i] * STR + skp[i]]) = pfA[i];
        *reinterpret_cast<double2*>(&Bt[srow[i] * STR + skp[i]]) = pfB[i];
      }
      __syncthreads();

      int nct = ct, nch = ch + 1;
      if (nch == 4) { nch = 0; ++nct; }
      if (nct < 4) {
        #pragma unroll
        for (int i = 0; i < 4; ++i) {
          pfA[i] = *reinterpret_cast<const double2*>(Abase + srow[i] * DD + nch * 32 + skp[i]);
          pfB[i] = *reinterpret_cast<const double2*>(Bbase + (long long)(nct * 64 + srow[i]) * DD + nch * 32 + skp[i]);
        }
      }

      #pragma unroll
      for (int k4 = 0; k4 < 8; ++k4) {
        const int kk = k4 * 4 + q;
        const double a = At[(16 * w + c16) * STR + kk];
        #pragma unroll
        for (int t = 0; t < 4; ++t) {
          const double bv = Bt[(16 * t + c16) * STR + kk];
          acc[t] = __builtin_amdgcn_mfma_f64_16x16x4f64(a, bv, acc[t], 0, 0, 0);
        }
      }
    }

    // fold using the CALIBRATED row/col mapping
    const int colbase = c0 + ct * 64;
    #pragma unroll
    for (int t = 0; t < 4; ++t)
      #pragma unroll
      for (int r = 0; r < 4; ++r)
        insert8(tv[r], ti[r], acc[t][r], colbase + 16 * t + colof[r]);
  }

  // merge across the 16 lanes of each k-lane group (they share the same 4 rows;
  // reg->row mapping is lane-invariant within the group under any 16x16 layout)
  #pragma unroll
  for (int m = 1; m <= 8; m <<= 1) {
    #pragma unroll
    for (int bb = 0; bb < 4; ++bb) {
      double ov[8]; int oi[8];
      #pragma unroll
      for (int s = 0; s < 8; ++s) {
        ov[s] = __shfl_xor(tv[bb][s], m, 64);
        oi[s] = __shfl_xor(ti[bb][s], m, 64);
      }
      #pragma unroll
      for (int s = 0; s < 8; ++s) insert8(tv[bb], ti[bb], ov[s], oi[s]);
    }
  }

  if (c16 == 0) {
    #pragma unroll
    for (int bb = 0; bb < 4; ++bb) {
      const long long base = ((long long)split * 16384 + row0 + 16 * w + rowof[bb]) * 8;
      #pragma unroll
      for (int s = 0; s < 8; ++s) {
        cand_v[base + s] = tv[bb][s];
        cand_i[base + s] = ti[bb][s];
      }
    }
  }
}

// ---------------- K4: merge 8 splits per row, scatter 1.0s symmetric ----------------
__global__ __launch_bounds__(256) void k_merge(const double* __restrict__ cand_v,
                                               const int* __restrict__ cand_i,
                                               float* __restrict__ out) {
  const long long r = (long long)blockIdx.x * 256 + threadIdx.x;  // 0..16383
  double fv[8]; int fi[8];
  #pragma unroll
  for (int s = 0; s < 8; ++s) { fv[s] = -DBL_MAX; fi[s] = 0x7fffffff; }
  for (int sp = 0; sp < 8; ++sp) {
    const long long base = ((long long)sp * 16384 + r) * 8;
    #pragma unroll
    for (int c = 0; c < 8; ++c) insert8(fv, fi, cand_v[base + c], cand_i[base + c]);
  }
  const int n = (int)(r & (NN - 1));
  const long long bbase = (r - n) * (long long)NN;   // b*N*N
  #pragma unroll
  for (int s = 0; s < 8; ++s) {
    const int m = fi[s];
    out[r * (long long)NN + m] = 1.0f;
    out[bbase + (long long)m * NN + n] = 1.0f;
  }
}

extern "C" void kernel_launch(void* const* d_in, const int* in_sizes, int n_in,
                              void* d_out, int out_size, void* d_ws, size_t ws_size,
                              hipStream_t stream) {
  const float* x = (const float*)d_in[0];
  float* out = (float*)d_out;
  char* ws = (char*)d_ws;
  double* normed = (double*)ws;                              // 16,777,216 B
  double* cand_v = (double*)(ws + 16777216);                 //  8,388,608 B
  int* cand_i = (int*)(ws + 16777216 + 8388608);             //  4,194,304 B

  hipLaunchKernelGGL(k_normalize, dim3(BATCH * NN / 4), dim3(256), 0, stream, x, normed);
  hipLaunchKernelGGL(k_zero_diag, dim3((unsigned)((long long)BATCH * NN * NN / 4 / 256)),
                     dim3(256), 0, stream, out);
  hipLaunchKernelGGL(k_scores_topk, dim3(2048), dim3(256), 0, stream, normed, cand_v, cand_i);
  hipLaunchKernelGGL(k_merge, dim3(64), dim3(256), 0, stream, cand_v, cand_i, out);
}

// Round 4
// 523.867 us; speedup vs baseline: 1.6312x; 1.6312x over previous
//
#include <hip/hip_runtime.h>
#include <cstdint>
#include <cfloat>

#define NN 2048
#define DD 128
#define BATCH 8
#define TC 32            // cols per LDS tile
#define NSTEPS 32        // 1024 cols per block / TC

typedef double d4 __attribute__((ext_vector_type(4)));

// ---------------- K1: fp64 L2-normalize rows ----------------
__global__ __launch_bounds__(256) void k_normalize(const float* __restrict__ x,
                                                   double* __restrict__ normed) {
  const int wave = threadIdx.x >> 6;
  const int lane = threadIdx.x & 63;
  const long long row = (long long)blockIdx.x * 4 + wave;   // 16384 rows
  float2 v = reinterpret_cast<const float2*>(x + row * DD)[lane];
  const double d0 = (double)v.x, d1 = (double)v.y;
  double s = d0 * d0 + d1 * d1;
  #pragma unroll
  for (int m = 32; m >= 1; m >>= 1) s += __shfl_xor(s, m, 64);
  double denom = sqrt(s);
  denom = denom > 1e-12 ? denom : 1e-12;
  double2 o;
  o.x = d0 / denom;
  o.y = d1 / denom;
  reinterpret_cast<double2*>(normed + row * DD)[lane] = o;
}

// ---------------- K2: zero-fill output + diagonal ----------------
__global__ __launch_bounds__(256) void k_zero_diag(float* __restrict__ out) {
  const long long g = (long long)blockIdx.x * 256 + threadIdx.x;  // float4 id
  const long long p0 = g * 4;
  const int c0 = (int)(p0 & (NN - 1));
  const long long r = p0 >> 11;
  const int n = (int)(r & (NN - 1));
  float4 v;
  v.x = (c0 + 0 == n) ? 1.0f : 0.0f;
  v.y = (c0 + 1 == n) ? 1.0f : 0.0f;
  v.z = (c0 + 2 == n) ? 1.0f : 0.0f;
  v.w = (c0 + 3 == n) ? 1.0f : 0.0f;
  reinterpret_cast<float4*>(out)[g] = v;
}

// Sorted-desc top-8 insertion, tie-break by smaller index (matches jax.lax.top_k).
__device__ __forceinline__ void insert8(double (&v)[8], int (&ix)[8], double nv, int nm) {
  const bool better = (nv > v[7]) || (nv == v[7] && nm < ix[7]);
  if (better) {
    v[7] = nv; ix[7] = nm;
    #pragma unroll
    for (int q = 7; q >= 1; --q) {
      const bool sw = (v[q] > v[q - 1]) || (v[q] == v[q - 1] && ix[q] < ix[q - 1]);
      const double va = v[q - 1], vb = v[q];
      const int ia = ix[q - 1], ib = ix[q];
      v[q - 1] = sw ? vb : va;  v[q] = sw ? va : vb;
      ix[q - 1] = sw ? ib : ia; ix[q] = sw ? ia : ib;
    }
  }
}

// ---------------- K3: fp64 MFMA scores + per-split top-8 candidates ----------------
// grid: 512 blocks = 256 row-tiles (64 rows) x 2 col-splits (1024 cols).
// A (64 rows x K=128) held in registers per wave; B streamed through a
// double-buffered 32-col x 128-k LDS tile (XOR-swizzled), 1 barrier/tile.
// k remapped so lane-quad q owns k in [32q, 32q+32) -> b128 LDS reads.
__global__ __launch_bounds__(256, 2) void k_scores_topk(const double* __restrict__ normed,
                                                        double* __restrict__ cand_v,
                                                        int* __restrict__ cand_i) {
  __shared__ __align__(16) double2 Btile[2][TC * 64];   // 2 x 32 KB

  const int tid = threadIdx.x;
  const int w = tid >> 6;        // wave 0..3
  const int l = tid & 63;
  const int q = l >> 4;          // lane-quad: owns k in [32q, 32q+32)
  const int c16 = l & 15;
  const int key = c16 & 7;       // read-side XOR swizzle key (= col&7 since cols are 16t+c16)

  // --- runtime calibration of the f64 MFMA C/D fragment layout (validated R3) ---
  const double k0 = (l < 16) ? 1.0 : 0.0;
  d4 zac = {0.0, 0.0, 0.0, 0.0};
  const d4 dprobe_r = __builtin_amdgcn_mfma_f64_16x16x4f64(k0 * (double)(c16 + 1), k0, zac, 0, 0, 0);
  const d4 dprobe_c = __builtin_amdgcn_mfma_f64_16x16x4f64(k0, k0 * (double)(c16 + 1), zac, 0, 0, 0);
  int rowof[4], colof[4];
  #pragma unroll
  for (int r = 0; r < 4; ++r) {
    rowof[r] = (int)dprobe_r[r] - 1;
    colof[r] = (int)dprobe_c[r] - 1;
  }

  const int rowblk = blockIdx.x >> 1;
  const int split = blockIdx.x & 1;
  const long long row0 = (long long)rowblk * 64;
  const int b = (int)(row0 >> 11);
  const int c0 = split * 1024;
  const double* Bbase = normed + ((long long)b * NN + c0) * DD;

  // ---- A fragments in registers: lane (w,q,c16) holds A[row0+16w+c16][32q + 2s2 (+1)] ----
  double2 areg[16];
  {
    const double* Arow = normed + (row0 + 16 * w + c16) * DD + 32 * q;
    #pragma unroll
    for (int i = 0; i < 16; ++i)
      areg[i] = reinterpret_cast<const double2*>(Arow)[i];
  }

  // staging role: thread p stages col c = p>>3, double2 slots j = (p&7) + 8i
  const int sc = tid >> 3;
  const int sj0 = tid & 7;
  const int skey = sc & 7;       // write-side swizzle key

  // top-8 state: lane owns rows 16w + rowof[bb]
  double tv[4][8]; int ti[4][8];
  #pragma unroll
  for (int bb = 0; bb < 4; ++bb)
    #pragma unroll
    for (int s = 0; s < 8; ++s) { tv[bb][s] = -DBL_MAX; ti[bb][s] = 0x7fffffff; }

  // ---- prologue: stage tile 0 into buffer 0 ----
  double2 pf[8];
  {
    const double* colp = Bbase + (long long)sc * DD;
    #pragma unroll
    for (int i = 0; i < 8; ++i)
      pf[i] = reinterpret_cast<const double2*>(colp)[sj0 + 8 * i];
    #pragma unroll
    for (int i = 0; i < 8; ++i) {
      const int j = sj0 + 8 * i;
      Btile[0][sc * 64 + (j ^ skey)] = pf[i];
    }
  }

  for (int ts = 0; ts < NSTEPS; ++ts) {
    // issue global prefetch for tile ts+1 (drains under this tile's MFMAs)
    if (ts + 1 < NSTEPS) {
      const double* colp = Bbase + (long long)((ts + 1) * TC + sc) * DD;
      #pragma unroll
      for (int i = 0; i < 8; ++i)
        pf[i] = reinterpret_cast<const double2*>(colp)[sj0 + 8 * i];
    }

    __syncthreads();   // tile ts fully staged; all waves done reading buffer (ts+1)&1

    const double2* Bt = Btile[ts & 1];
    d4 acc[2];
    acc[0] = (d4){0.0, 0.0, 0.0, 0.0};
    acc[1] = (d4){0.0, 0.0, 0.0, 0.0};

    #pragma unroll
    for (int s2 = 0; s2 < 16; ++s2) {
      const int jsw = (16 * q + s2) ^ key;
      const double2 a = areg[s2];
      #pragma unroll
      for (int t = 0; t < 2; ++t) {
        const double2 bv = Bt[(16 * t + c16) * 64 + jsw];
        acc[t] = __builtin_amdgcn_mfma_f64_16x16x4f64(a.x, bv.x, acc[t], 0, 0, 0);
        acc[t] = __builtin_amdgcn_mfma_f64_16x16x4f64(a.y, bv.y, acc[t], 0, 0, 0);
      }
    }

    // fold this tile's scores into running top-8 (calibrated layout)
    const int colbase = c0 + ts * TC;
    #pragma unroll
    for (int t = 0; t < 2; ++t)
      #pragma unroll
      for (int r = 0; r < 4; ++r)
        insert8(tv[r], ti[r], acc[t][r], colbase + 16 * t + colof[r]);

    // write staged tile ts+1 into the other buffer (race-free: barrier gates readers)
    if (ts + 1 < NSTEPS) {
      double2* Bw = Btile[(ts + 1) & 1];
      #pragma unroll
      for (int i = 0; i < 8; ++i) {
        const int j = sj0 + 8 * i;
        Bw[sc * 64 + (j ^ skey)] = pf[i];
      }
    }
  }

  // merge across the 16 lanes of each lane-quad (rows identical within quad)
  #pragma unroll
  for (int m = 1; m <= 8; m <<= 1) {
    #pragma unroll
    for (int bb = 0; bb < 4; ++bb) {
      double ov[8]; int oi[8];
      #pragma unroll
      for (int s = 0; s < 8; ++s) {
        ov[s] = __shfl_xor(tv[bb][s], m, 64);
        oi[s] = __shfl_xor(ti[bb][s], m, 64);
      }
      #pragma unroll
      for (int s = 0; s < 8; ++s) insert8(tv[bb], ti[bb], ov[s], oi[s]);
    }
  }

  if (c16 == 0) {
    #pragma unroll
    for (int bb = 0; bb < 4; ++bb) {
      const long long base = ((long long)split * 16384 + row0 + 16 * w + rowof[bb]) * 8;
      #pragma unroll
      for (int s = 0; s < 8; ++s) {
        cand_v[base + s] = tv[bb][s];
        cand_i[base + s] = ti[bb][s];
      }
    }
  }
}

// ---------------- K4: merge 2 splits per row, scatter 1.0s symmetric ----------------
__global__ __launch_bounds__(256) void k_merge(const double* __restrict__ cand_v,
                                               const int* __restrict__ cand_i,
                                               float* __restrict__ out) {
  const long long r = (long long)blockIdx.x * 256 + threadIdx.x;  // 0..16383
  double fv[8]; int fi[8];
  #pragma unroll
  for (int s = 0; s < 8; ++s) { fv[s] = -DBL_MAX; fi[s] = 0x7fffffff; }
  for (int sp = 0; sp < 2; ++sp) {
    const long long base = ((long long)sp * 16384 + r) * 8;
    #pragma unroll
    for (int c = 0; c < 8; ++c) insert8(fv, fi, cand_v[base + c], cand_i[base + c]);
  }
  const int n = (int)(r & (NN - 1));
  const long long bbase = (r - n) * (long long)NN;   // b*N*N
  #pragma unroll
  for (int s = 0; s < 8; ++s) {
    const int m = fi[s];
    out[r * (long long)NN + m] = 1.0f;
    out[bbase + (long long)m * NN + n] = 1.0f;
  }
}

extern "C" void kernel_launch(void* const* d_in, const int* in_sizes, int n_in,
                              void* d_out, int out_size, void* d_ws, size_t ws_size,
                              hipStream_t stream) {
  const float* x = (const float*)d_in[0];
  float* out = (float*)d_out;
  char* ws = (char*)d_ws;
  double* normed = (double*)ws;                              // 16,777,216 B
  double* cand_v = (double*)(ws + 16777216);                 //  2,097,152 B (2 x 16384 x 8)
  int* cand_i = (int*)(ws + 16777216 + 2097152);             //  1,048,576 B

  hipLaunchKernelGGL(k_normalize, dim3(BATCH * NN / 4), dim3(256), 0, stream, x, normed);
  hipLaunchKernelGGL(k_zero_diag, dim3((unsigned)((long long)BATCH * NN * NN / 4 / 256)),
                     dim3(256), 0, stream, out);
  hipLaunchKernelGGL(k_scores_topk, dim3(512), dim3(256), 0, stream, normed, cand_v, cand_i);
  hipLaunchKernelGGL(k_merge, dim3(64), dim3(256), 0, stream, cand_v, cand_i, out);
}

// Round 5
// 444.540 us; speedup vs baseline: 1.9222x; 1.1784x over previous
//
#include <hip/hip_runtime.h>
#include <cstdint>
#include <cfloat>

#define NN 2048
#define DD 128
#define BATCH 8
#define TC 32            // cols per LDS tile
#define NSTEPS 32        // 1024 cols per block / TC

typedef double d4 __attribute__((ext_vector_type(4)));
typedef unsigned long long u64;

// ---------------- K1: fp64 L2-normalize rows ----------------
__global__ __launch_bounds__(256) void k_normalize(const float* __restrict__ x,
                                                   double* __restrict__ normed) {
  const int wave = threadIdx.x >> 6;
  const int lane = threadIdx.x & 63;
  const long long row = (long long)blockIdx.x * 4 + wave;   // 16384 rows
  float2 v = reinterpret_cast<const float2*>(x + row * DD)[lane];
  const double d0 = (double)v.x, d1 = (double)v.y;
  double s = d0 * d0 + d1 * d1;
  #pragma unroll
  for (int m = 32; m >= 1; m >>= 1) s += __shfl_xor(s, m, 64);
  double denom = sqrt(s);
  denom = denom > 1e-12 ? denom : 1e-12;
  double2 o;
  o.x = d0 / denom;
  o.y = d1 / denom;
  reinterpret_cast<double2*>(normed + row * DD)[lane] = o;
}

// ---------------- K2: zero-fill output + diagonal ----------------
__global__ __launch_bounds__(256) void k_zero_diag(float* __restrict__ out) {
  const long long g = (long long)blockIdx.x * 256 + threadIdx.x;  // float4 id
  const long long p0 = g * 4;
  const int c0 = (int)(p0 & (NN - 1));
  const long long r = p0 >> 11;
  const int n = (int)(r & (NN - 1));
  float4 v;
  v.x = (c0 + 0 == n) ? 1.0f : 0.0f;
  v.y = (c0 + 1 == n) ? 1.0f : 0.0f;
  v.z = (c0 + 2 == n) ? 1.0f : 0.0f;
  v.w = (c0 + 3 == n) ? 1.0f : 0.0f;
  reinterpret_cast<float4*>(out)[g] = v;
}

// ---- sortable u64 key: monotone-mapped fp64 score bits, low 11 bits = 2047-col ----
// larger key  <=>  (score larger) OR (score equal-after-trunc AND col smaller)
// trunc error 2^-41 rel (~5e-13) << min 8th/9th score gap (~1e-7): selection-exact.
__device__ __forceinline__ u64 make_key(double s, int col) {
  u64 u = (u64)__double_as_longlong(s);
  const u64 m = (u64)((long long)u >> 63);          // all-ones if negative
  u ^= (m | 0x8000000000000000ull);                  // monotone map
  return (u & ~2047ull) | (u64)(2047 - col);
}

// sorted-desc top-8 insertion on u64 keys
__device__ __forceinline__ void insert8u(u64 (&v)[8], u64 nk) {
  if (nk > v[7]) {
    v[7] = nk;
    #pragma unroll
    for (int q = 7; q >= 1; --q) {
      const u64 a = v[q - 1], b = v[q];
      const bool sw = b > a;
      v[q - 1] = sw ? b : a;
      v[q] = sw ? a : b;
    }
  }
}

__device__ __forceinline__ u64 umax64(u64 a, u64 b) { return a > b ? a : b; }
__device__ __forceinline__ u64 umin64(u64 a, u64 b) { return a > b ? b : a; }
#define CEX(i, j) { const u64 ta = L[i], tb = L[j]; L[i] = umax64(ta, tb); L[j] = umin64(ta, tb); }

// merge two sorted-desc 8-lists -> kv = top-8 sorted desc (bitonic merge)
__device__ __forceinline__ void merge8(u64 (&kv)[8], const u64 (&ov)[8]) {
  u64 L[8];
  #pragma unroll
  for (int i = 0; i < 8; ++i) L[i] = umax64(kv[i], ov[7 - i]);   // bitonic split
  CEX(0, 4) CEX(1, 5) CEX(2, 6) CEX(3, 7)
  CEX(0, 2) CEX(1, 3) CEX(4, 6) CEX(5, 7)
  CEX(0, 1) CEX(2, 3) CEX(4, 5) CEX(6, 7)
  #pragma unroll
  for (int i = 0; i < 8; ++i) kv[i] = L[i];
}

// ---------------- K3: fp64 MFMA scores + per-split top-8 candidates ----------------
// grid: 512 blocks = 256 row-tiles (64 rows) x 2 col-splits (1024 cols).
// A in registers; B double-buffered 32-col x 128-k LDS tile, 1 barrier/tile.
// Tail (top-8 fold of tile ts-1) runs under tile ts's MFMAs (separate acc regs).
__global__ __launch_bounds__(256, 2) void k_scores_topk(const double* __restrict__ normed,
                                                        u64* __restrict__ cand) {
  __shared__ __align__(16) double2 Btile[2][TC * 64];   // 2 x 32 KB

  const int tid = threadIdx.x;
  const int w = tid >> 6;
  const int l = tid & 63;
  const int q = l >> 4;          // lane-quad: owns k in [32q, 32q+32)
  const int c16 = l & 15;
  const int key = c16 & 7;       // read-side XOR swizzle key

  // --- runtime calibration of the f64 MFMA C/D layout (validated R3/R4) ---
  const double k0 = (l < 16) ? 1.0 : 0.0;
  d4 zac = {0.0, 0.0, 0.0, 0.0};
  const d4 dprobe_r = __builtin_amdgcn_mfma_f64_16x16x4f64(k0 * (double)(c16 + 1), k0, zac, 0, 0, 0);
  const d4 dprobe_c = __builtin_amdgcn_mfma_f64_16x16x4f64(k0, k0 * (double)(c16 + 1), zac, 0, 0, 0);
  int rowof[4], colof[4];
  #pragma unroll
  for (int r = 0; r < 4; ++r) {
    rowof[r] = (int)dprobe_r[r] - 1;
    colof[r] = (int)dprobe_c[r] - 1;
  }

  const int rowblk = blockIdx.x >> 1;
  const int split = blockIdx.x & 1;
  const long long row0 = (long long)rowblk * 64;
  const int b = (int)(row0 >> 11);
  const int c0 = split * 1024;
  const double* Bbase = normed + ((long long)b * NN + c0) * DD;

  // A fragments in registers: lane holds A[row0+16w+c16][32q + 2s2 (+1)]
  double2 areg[16];
  {
    const double* Arow = normed + (row0 + 16 * w + c16) * DD + 32 * q;
    #pragma unroll
    for (int i = 0; i < 16; ++i)
      areg[i] = reinterpret_cast<const double2*>(Arow)[i];
  }

  // staging role: thread stages col sc, double2 slots j = sj0 + 8i
  const int sc = tid >> 3;
  const int sj0 = tid & 7;
  const int skey = sc & 7;

  u64 kv[4][8];
  #pragma unroll
  for (int bb = 0; bb < 4; ++bb)
    #pragma unroll
    for (int s = 0; s < 8; ++s) kv[bb][s] = 0ull;    // sentinel: below any real key

  // ---- prologue: stage tile 0 into buffer 0 (first loop barrier gates readers) ----
  double2 pf[8];
  {
    const double* colp = Bbase + (long long)sc * DD;
    #pragma unroll
    for (int i = 0; i < 8; ++i)
      pf[i] = reinterpret_cast<const double2*>(colp)[sj0 + 8 * i];
    #pragma unroll
    for (int i = 0; i < 8; ++i) {
      const int j = sj0 + 8 * i;
      Btile[0][sc * 64 + (j ^ skey)] = pf[i];
    }
  }

  d4 accP[2];            // previous tile's accumulators (tail input)
  int colbaseP = 0;

  for (int ts = 0; ts < NSTEPS; ++ts) {
    __syncthreads();     // tile ts staged; all waves done reading buffer (ts+1)&1
                         // (no outstanding vmem here -> barrier drain is free)

    // issue global prefetch AFTER the barrier: lands under this tile's MFMAs
    if (ts + 1 < NSTEPS) {
      const double* colp = Bbase + (long long)((ts + 1) * TC + sc) * DD;
      #pragma unroll
      for (int i = 0; i < 8; ++i)
        pf[i] = reinterpret_cast<const double2*>(colp)[sj0 + 8 * i];
    }

    const double2* Bt = Btile[ts & 1];
    d4 accC[2];
    accC[0] = (d4){0.0, 0.0, 0.0, 0.0};
    accC[1] = (d4){0.0, 0.0, 0.0, 0.0};

    #pragma unroll
    for (int s2 = 0; s2 < 16; ++s2) {
      const int jsw = (16 * q + s2) ^ key;
      const double2 a = areg[s2];
      #pragma unroll
      for (int t = 0; t < 2; ++t) {
        const double2 bv = Bt[(16 * t + c16) * 64 + jsw];
        accC[t] = __builtin_amdgcn_mfma_f64_16x16x4f64(a.x, bv.x, accC[t], 0, 0, 0);
        accC[t] = __builtin_amdgcn_mfma_f64_16x16x4f64(a.y, bv.y, accC[t], 0, 0, 0);
      }
    }

    // tail for PREVIOUS tile — independent of accC chains, overlaps the MFMAs
    if (ts > 0) {
      #pragma unroll
      for (int t = 0; t < 2; ++t)
        #pragma unroll
        for (int r = 0; r < 4; ++r)
          insert8u(kv[r], make_key(accP[t][r], colbaseP + 16 * t + colof[r]));
    }
    accP[0] = accC[0];
    accP[1] = accC[1];
    colbaseP = c0 + ts * TC;

    // stage tile ts+1 (vmcnt wait lands here, ~8k cy after issue)
    if (ts + 1 < NSTEPS) {
      double2* Bw = Btile[(ts + 1) & 1];
      #pragma unroll
      for (int i = 0; i < 8; ++i) {
        const int j = sj0 + 8 * i;
        Bw[sc * 64 + (j ^ skey)] = pf[i];
      }
    }
  }

  // epilogue fold: last tile
  #pragma unroll
  for (int t = 0; t < 2; ++t)
    #pragma unroll
    for (int r = 0; r < 4; ++r)
      insert8u(kv[r], make_key(accP[t][r], colbaseP + 16 * t + colof[r]));

  // merge across the 16 lanes of each lane-quad (bitonic list merges)
  #pragma unroll
  for (int m = 1; m <= 8; m <<= 1) {
    #pragma unroll
    for (int bb = 0; bb < 4; ++bb) {
      u64 ov[8];
      #pragma unroll
      for (int s = 0; s < 8; ++s) ov[s] = __shfl_xor(kv[bb][s], m, 64);
      merge8(kv[bb], ov);
    }
  }

  if (c16 == 0) {
    #pragma unroll
    for (int bb = 0; bb < 4; ++bb) {
      const long long base = ((long long)split * 16384 + row0 + 16 * w + rowof[bb]) * 8;
      #pragma unroll
      for (int s = 0; s < 8; ++s) cand[base + s] = kv[bb][s];
    }
  }
}

// ---------------- K4: merge 2 splits per row, scatter 1.0s symmetric ----------------
__global__ __launch_bounds__(256) void k_merge(const u64* __restrict__ cand,
                                               float* __restrict__ out) {
  const long long r = (long long)blockIdx.x * 256 + threadIdx.x;  // 0..16383
  u64 kv[8], ov[8];
  #pragma unroll
  for (int s = 0; s < 8; ++s) kv[s] = cand[r * 8 + s];
  #pragma unroll
  for (int s = 0; s < 8; ++s) ov[s] = cand[(16384 + r) * 8 + s];
  merge8(kv, ov);
  const int n = (int)(r & (NN - 1));
  const long long bbase = (r - n) * (long long)NN;   // b*N*N
  #pragma unroll
  for (int s = 0; s < 8; ++s) {
    const int m = 2047 - (int)(kv[s] & 2047ull);
    out[r * (long long)NN + m] = 1.0f;
    out[bbase + (long long)m * NN + n] = 1.0f;
  }
}

extern "C" void kernel_launch(void* const* d_in, const int* in_sizes, int n_in,
                              void* d_out, int out_size, void* d_ws, size_t ws_size,
                              hipStream_t stream) {
  const float* x = (const float*)d_in[0];
  float* out = (float*)d_out;
  char* ws = (char*)d_ws;
  double* normed = (double*)ws;                 // 16,777,216 B
  u64* cand = (u64*)(ws + 16777216);            //  2,097,152 B (2 x 16384 x 8 keys)

  hipLaunchKernelGGL(k_normalize, dim3(BATCH * NN / 4), dim3(256), 0, stream, x, normed);
  hipLaunchKernelGGL(k_zero_diag, dim3((unsigned)((long long)BATCH * NN * NN / 4 / 256)),
                     dim3(256), 0, stream, out);
  hipLaunchKernelGGL(k_scores_topk, dim3(512), dim3(256), 0, stream, normed, cand);
  hipLaunchKernelGGL(k_merge, dim3(64), dim3(256), 0, stream, cand, out);
}

// Round 6
// 413.361 us; speedup vs baseline: 2.0672x; 1.0754x over previous
//
#include <hip/hip_runtime.h>
#include <cstdint>
#include <cfloat>

#define NN 2048
#define DD 128
#define BATCH 8
#define TC 32            // cols per LDS tile
#define NSTEPS 32        // 1024 cols per block / TC

typedef double d4 __attribute__((ext_vector_type(4)));
typedef unsigned long long u64;

// ---------------- K1: fp64 L2-normalize rows ----------------
__global__ __launch_bounds__(256) void k_normalize(const float* __restrict__ x,
                                                   double* __restrict__ normed) {
  const int wave = threadIdx.x >> 6;
  const int lane = threadIdx.x & 63;
  const long long row = (long long)blockIdx.x * 4 + wave;   // 16384 rows
  float2 v = reinterpret_cast<const float2*>(x + row * DD)[lane];
  const double d0 = (double)v.x, d1 = (double)v.y;
  double s = d0 * d0 + d1 * d1;
  #pragma unroll
  for (int m = 32; m >= 1; m >>= 1) s += __shfl_xor(s, m, 64);
  double denom = sqrt(s);
  denom = denom > 1e-12 ? denom : 1e-12;
  double2 o;
  o.x = d0 / denom;
  o.y = d1 / denom;
  reinterpret_cast<double2*>(normed + row * DD)[lane] = o;
}

// ---------------- K2: zero-fill output + diagonal ----------------
__global__ __launch_bounds__(256) void k_zero_diag(float* __restrict__ out) {
  const long long g = (long long)blockIdx.x * 256 + threadIdx.x;  // float4 id
  const long long p0 = g * 4;
  const int c0 = (int)(p0 & (NN - 1));
  const long long r = p0 >> 11;
  const int n = (int)(r & (NN - 1));
  float4 v;
  v.x = (c0 + 0 == n) ? 1.0f : 0.0f;
  v.y = (c0 + 1 == n) ? 1.0f : 0.0f;
  v.z = (c0 + 2 == n) ? 1.0f : 0.0f;
  v.w = (c0 + 3 == n) ? 1.0f : 0.0f;
  reinterpret_cast<float4*>(out)[g] = v;
}

// ---- sortable u64 key: monotone fp64 bits, low 11 bits = 2047-col (R5-validated) ----
__device__ __forceinline__ u64 make_key(double s, int col) {
  u64 u = (u64)__double_as_longlong(s);
  const u64 m = (u64)((long long)u >> 63);
  u ^= (m | 0x8000000000000000ull);
  return (u & ~2047ull) | (u64)(2047 - col);
}

__device__ __forceinline__ u64 umax64(u64 a, u64 b) { return a > b ? a : b; }
__device__ __forceinline__ u64 umin64(u64 a, u64 b) { return a > b ? b : a; }

// Batcher odd-even merge sort, 8 keys desc, 19 compare-exchanges, branch-free
__device__ __forceinline__ void sort8(u64 (&L)[8]) {
#define CX(i, j) { const u64 a = L[i], b = L[j]; L[i] = umax64(a, b); L[j] = umin64(a, b); }
  CX(0, 1) CX(2, 3) CX(4, 5) CX(6, 7)
  CX(0, 2) CX(1, 3) CX(4, 6) CX(5, 7)
  CX(1, 2) CX(5, 6)
  CX(0, 4) CX(1, 5) CX(2, 6) CX(3, 7)
  CX(2, 4) CX(3, 5)
  CX(1, 2) CX(3, 4) CX(5, 6)
#undef CX
}

// merge two sorted-desc 8-lists -> kv = top-8 sorted desc (bitonic)
__device__ __forceinline__ void merge8(u64 (&kv)[8], const u64 (&ov)[8]) {
  u64 L[8];
  #pragma unroll
  for (int i = 0; i < 8; ++i) L[i] = umax64(kv[i], ov[7 - i]);
#define CX(i, j) { const u64 a = L[i], b = L[j]; L[i] = umax64(a, b); L[j] = umin64(a, b); }
  CX(0, 4) CX(1, 5) CX(2, 6) CX(3, 7)
  CX(0, 2) CX(1, 3) CX(4, 6) CX(5, 7)
  CX(0, 1) CX(2, 3) CX(4, 5) CX(6, 7)
#undef CX
  #pragma unroll
  for (int i = 0; i < 8; ++i) kv[i] = L[i];
}

// ---------------- K3: fp64 MFMA scores + per-split top-8 candidates ----------------
// grid: 512 blocks = 256 row-tiles (64 rows) x 2 col-splits (1024 cols).
// A in registers; B double-buffered 32x128 LDS tile, 1 barrier/tile.
// Accumulators round-trip a per-wave LDS score buffer each step, so the top-k
// tail works on ONE row per lane (kv[8], 16 VGPR) -> no register spill.
__global__ __launch_bounds__(256, 2) void k_scores_topk(const double* __restrict__ normed,
                                                        u64* __restrict__ cand) {
  __shared__ __align__(16) double2 Btile[2][TC * 64];   // 65536 B
  __shared__ __align__(16) double Sbuf[4][16 * 32];     // 16384 B (per-wave 16 rows x 32 cols)

  const int tid = threadIdx.x;
  const int w = tid >> 6;
  const int l = tid & 63;
  const int q = l >> 4;          // lane-quad: owns k in [32q, 32q+32)
  const int c16 = l & 15;
  const int key = c16 & 7;       // Btile read-side XOR swizzle key

  // --- runtime calibration of the f64 MFMA C/D layout (validated R3-R5) ---
  const double k0 = (l < 16) ? 1.0 : 0.0;
  d4 zac = {0.0, 0.0, 0.0, 0.0};
  const d4 dprobe_r = __builtin_amdgcn_mfma_f64_16x16x4f64(k0 * (double)(c16 + 1), k0, zac, 0, 0, 0);
  const d4 dprobe_c = __builtin_amdgcn_mfma_f64_16x16x4f64(k0, k0 * (double)(c16 + 1), zac, 0, 0, 0);
  int rowof[4], colof[4];
  #pragma unroll
  for (int r = 0; r < 4; ++r) {
    rowof[r] = (int)dprobe_r[r] - 1;
    colof[r] = (int)dprobe_c[r] - 1;
  }

  const int rowblk = blockIdx.x >> 1;
  const int split = blockIdx.x & 1;
  const long long row0 = (long long)rowblk * 64;
  const int b = (int)(row0 >> 11);
  const int c0 = split * 1024;
  const double* Bbase = normed + ((long long)b * NN + c0) * DD;

  // A fragments in registers: lane holds A[row0+16w+c16][32q + 2s2 (+1)]
  double2 areg[16];
  {
    const double* Arow = normed + (row0 + 16 * w + c16) * DD + 32 * q;
    #pragma unroll
    for (int i = 0; i < 16; ++i)
      areg[i] = reinterpret_cast<const double2*>(Arow)[i];
  }

  // staging role: thread stages col sc, double2 slots j = sj0 + 8i
  const int sc = tid >> 3;
  const int sj0 = tid & 7;
  const int skey = sc & 7;

  // tail role: lane owns row rw; quarter j4 picks (tile-half, col-half)
  const int rw = c16;            // row 0..15 within wave
  const int tph = q >> 1;        // tile 0/1
  const int h8 = (q & 1) * 8;    // col-half base
  const int rkey = (rw & 7) << 1;  // Sbuf XOR swizzle (even -> preserves b128 pairs)

  u64 kv[8];
  #pragma unroll
  for (int s = 0; s < 8; ++s) kv[s] = 0ull;   // sentinel below any real key

  // ---- prologue: stage tile 0 into buffer 0 ----
  double2 pf[8];
  {
    const double* colp = Bbase + (long long)sc * DD;
    #pragma unroll
    for (int i = 0; i < 8; ++i)
      pf[i] = reinterpret_cast<const double2*>(colp)[sj0 + 8 * i];
    #pragma unroll
    for (int i = 0; i < 8; ++i) {
      const int j = sj0 + 8 * i;
      Btile[0][sc * 64 + (j ^ skey)] = pf[i];
    }
  }

  for (int ts = 0; ts < NSTEPS; ++ts) {
    __syncthreads();   // tile ts staged; all waves done reading buffer (ts+1)&1

    // prefetch AFTER the barrier: lands under this tile's MFMAs
    if (ts + 1 < NSTEPS) {
      const double* colp = Bbase + (long long)((ts + 1) * TC + sc) * DD;
      #pragma unroll
      for (int i = 0; i < 8; ++i)
        pf[i] = reinterpret_cast<const double2*>(colp)[sj0 + 8 * i];
    }

    const double2* Bt = Btile[ts & 1];
    d4 accC[2];
    accC[0] = (d4){0.0, 0.0, 0.0, 0.0};
    accC[1] = (d4){0.0, 0.0, 0.0, 0.0};

    #pragma unroll
    for (int s2 = 0; s2 < 16; ++s2) {
      const int jsw = (16 * q + s2) ^ key;
      const double2 a = areg[s2];
      #pragma unroll
      for (int t = 0; t < 2; ++t) {
        const double2 bv = Bt[(16 * t + c16) * 64 + jsw];
        accC[t] = __builtin_amdgcn_mfma_f64_16x16x4f64(a.x, bv.x, accC[t], 0, 0, 0);
        accC[t] = __builtin_amdgcn_mfma_f64_16x16x4f64(a.y, bv.y, accC[t], 0, 0, 0);
      }
    }

    // ---- tail for PREVIOUS tile: read 8 scores of row rw, fold into kv ----
    // (reads prev step's Sbuf writes; intra-wave LDS is in-order; overlaps MFMAs)
    if (ts > 0) {
      u64 nk[8];
      const int colb = c0 + (ts - 1) * TC + 16 * tph + h8;
      #pragma unroll
      for (int m = 0; m < 4; ++m) {
        const int c = 16 * tph + h8 + 2 * m;
        const double2 dv = *reinterpret_cast<const double2*>(&Sbuf[w][rw * 32 + (c ^ rkey)]);
        nk[2 * m] = make_key(dv.x, colb + 2 * m);
        nk[2 * m + 1] = make_key(dv.y, colb + 2 * m + 1);
      }
      sort8(nk);
      merge8(kv, nk);
    }

    // ---- write this step's accumulators into the score buffer ----
    #pragma unroll
    for (int t = 0; t < 2; ++t)
      #pragma unroll
      for (int r = 0; r < 4; ++r) {
        const int c = 16 * t + colof[r];
        Sbuf[w][rowof[r] * 32 + (c ^ ((rowof[r] & 7) << 1))] = accC[t][r];
      }

    // stage tile ts+1 (vmcnt wait lands here, well after issue)
    if (ts + 1 < NSTEPS) {
      double2* Bw = Btile[(ts + 1) & 1];
      #pragma unroll
      for (int i = 0; i < 8; ++i) {
        const int j = sj0 + 8 * i;
        Bw[sc * 64 + (j ^ skey)] = pf[i];
      }
    }
  }

  // ---- epilogue: fold the last tile's scores ----
  {
    u64 nk[8];
    const int colb = c0 + (NSTEPS - 1) * TC + 16 * tph + h8;
    #pragma unroll
    for (int m = 0; m < 4; ++m) {
      const int c = 16 * tph + h8 + 2 * m;
      const double2 dv = *reinterpret_cast<const double2*>(&Sbuf[w][rw * 32 + (c ^ rkey)]);
      nk[2 * m] = make_key(dv.x, colb + 2 * m);
      nk[2 * m + 1] = make_key(dv.y, colb + 2 * m + 1);
    }
    sort8(nk);
    merge8(kv, nk);
  }

  // merge the 4 lanes sharing each row (masks 16, 32)
  #pragma unroll
  for (int m = 16; m <= 32; m <<= 1) {
    u64 ov[8];
    #pragma unroll
    for (int s = 0; s < 8; ++s) ov[s] = __shfl_xor(kv[s], m, 64);
    merge8(kv, ov);
  }

  if (l < 16) {
    const long long base = ((long long)split * 16384 + row0 + 16 * w + rw) * 8;
    #pragma unroll
    for (int s = 0; s < 8; ++s) cand[base + s] = kv[s];
  }
}

// ---------------- K4: merge 2 splits per row, scatter 1.0s symmetric ----------------
__global__ __launch_bounds__(256) void k_merge(const u64* __restrict__ cand,
                                               float* __restrict__ out) {
  const long long r = (long long)blockIdx.x * 256 + threadIdx.x;  // 0..16383
  u64 kv[8], ov[8];
  #pragma unroll
  for (int s = 0; s < 8; ++s) kv[s] = cand[r * 8 + s];
  #pragma unroll
  for (int s = 0; s < 8; ++s) ov[s] = cand[(16384 + r) * 8 + s];
  merge8(kv, ov);
  const int n = (int)(r & (NN - 1));
  const long long bbase = (r - n) * (long long)NN;   // b*N*N
  #pragma unroll
  for (int s = 0; s < 8; ++s) {
    const int m = 2047 - (int)(kv[s] & 2047ull);
    out[r * (long long)NN + m] = 1.0f;
    out[bbase + (long long)m * NN + n] = 1.0f;
  }
}

extern "C" void kernel_launch(void* const* d_in, const int* in_sizes, int n_in,
                              void* d_out, int out_size, void* d_ws, size_t ws_size,
                              hipStream_t stream) {
  const float* x = (const float*)d_in[0];
  float* out = (float*)d_out;
  char* ws = (char*)d_ws;
  double* normed = (double*)ws;                 // 16,777,216 B
  u64* cand = (u64*)(ws + 16777216);            //  2,097,152 B (2 x 16384 x 8 keys)

  hipLaunchKernelGGL(k_normalize, dim3(BATCH * NN / 4), dim3(256), 0, stream, x, normed);
  hipLaunchKernelGGL(k_zero_diag, dim3((unsigned)((long long)BATCH * NN * NN / 4 / 256)),
                     dim3(256), 0, stream, out);
  hipLaunchKernelGGL(k_scores_topk, dim3(512), dim3(256), 0, stream, normed, cand);
  hipLaunchKernelGGL(k_merge, dim3(64), dim3(256), 0, stream, cand, out);
}

// Round 7
// 388.069 us; speedup vs baseline: 2.2020x; 1.0652x over previous
//
#include <hip/hip_runtime.h>
#include <cstdint>
#include <cfloat>

#define NN 2048
#define DD 128
#define BATCH 8
#define NTILES 64        // 16-col tiles per wave-job (1024 cols / 16)

typedef double d4 __attribute__((ext_vector_type(4)));
typedef unsigned long long u64;

// ---------------- K1: fp64 L2-normalize rows ----------------
__global__ __launch_bounds__(256) void k_normalize(const float* __restrict__ x,
                                                   double* __restrict__ normed) {
  const int wave = threadIdx.x >> 6;
  const int lane = threadIdx.x & 63;
  const long long row = (long long)blockIdx.x * 4 + wave;   // 16384 rows
  float2 v = reinterpret_cast<const float2*>(x + row * DD)[lane];
  const double d0 = (double)v.x, d1 = (double)v.y;
  double s = d0 * d0 + d1 * d1;
  #pragma unroll
  for (int m = 32; m >= 1; m >>= 1) s += __shfl_xor(s, m, 64);
  double denom = sqrt(s);
  denom = denom > 1e-12 ? denom : 1e-12;
  double2 o;
  o.x = d0 / denom;
  o.y = d1 / denom;
  reinterpret_cast<double2*>(normed + row * DD)[lane] = o;
}

// ---- sortable u64 key: monotone fp64 bits, low 11 bits = 2047-col (validated R5/R6) ----
__device__ __forceinline__ u64 make_key(double s, int col) {
  u64 u = (u64)__double_as_longlong(s);
  const u64 m = (u64)((long long)u >> 63);
  u ^= (m | 0x8000000000000000ull);
  return (u & ~2047ull) | (u64)(2047 - col);
}

__device__ __forceinline__ u64 umax64(u64 a, u64 b) { return a > b ? a : b; }
__device__ __forceinline__ u64 umin64(u64 a, u64 b) { return a > b ? b : a; }

// merge two sorted-desc 8-lists -> kv = top-8 sorted desc (bitonic)
__device__ __forceinline__ void merge8(u64 (&kv)[8], const u64 (&ov)[8]) {
  u64 L[8];
  #pragma unroll
  for (int i = 0; i < 8; ++i) L[i] = umax64(kv[i], ov[7 - i]);
#define CX(i, j) { const u64 a = L[i], b = L[j]; L[i] = umax64(a, b); L[j] = umin64(a, b); }
  CX(0, 4) CX(1, 5) CX(2, 6) CX(3, 7)
  CX(0, 2) CX(1, 3) CX(4, 6) CX(5, 7)
  CX(0, 1) CX(2, 3) CX(4, 5) CX(6, 7)
#undef CX
  #pragma unroll
  for (int i = 0; i < 8; ++i) kv[i] = L[i];
}

// fold 4 new keys (unsorted) into kv: sort4 desc + bitonic merge with zero-pad
__device__ __forceinline__ void fold4(u64 (&kv)[8], u64 n0, u64 n1, u64 n2, u64 n3) {
  u64 nk[8];
  nk[0] = n0; nk[1] = n1; nk[2] = n2; nk[3] = n3;
  nk[4] = 0ull; nk[5] = 0ull; nk[6] = 0ull; nk[7] = 0ull;
#define CX(i, j) { const u64 a = nk[i], b = nk[j]; nk[i] = umax64(a, b); nk[j] = umin64(a, b); }
  CX(0, 1) CX(2, 3) CX(0, 2) CX(1, 3) CX(1, 2)
#undef CX
  merge8(kv, nk);
}

// ---------------- K3: barrier-free fp64 MFMA Gram + top-8 ----------------
// grid: 512 blocks = 256 row-tiles (64 rows) x 2 col-splits (1024 cols).
// Wave w owns 16 rows; zero LDS, zero __syncthreads. Operand trick for Gram:
// mfma(a = B-cols frag, b = A-rows frag) -> D[col][row]; each lane's 4 acc
// regs all belong to ONE row (row = colof = lane&15), cols = rowof[r].
// Both fragments load with the identical natural row-major pattern.
__global__ __launch_bounds__(256, 2) void k_scores_topk(const double* __restrict__ normed,
                                                        u64* __restrict__ cand) {
  const int tid = threadIdx.x;
  const int w = tid >> 6;
  const int l = tid & 63;
  const int q = l >> 4;          // lane-quad: owns k in [32q, 32q+32) (commutes over k)
  const int c16 = l & 15;

  // --- runtime calibration of the f64 MFMA C/D layout (validated R3-R6) ---
  const double k0 = (l < 16) ? 1.0 : 0.0;
  d4 zac = {0.0, 0.0, 0.0, 0.0};
  const d4 dprobe_r = __builtin_amdgcn_mfma_f64_16x16x4f64(k0 * (double)(c16 + 1), k0, zac, 0, 0, 0);
  const d4 dprobe_c = __builtin_amdgcn_mfma_f64_16x16x4f64(k0, k0 * (double)(c16 + 1), zac, 0, 0, 0);
  int rowof[4];
  #pragma unroll
  for (int r = 0; r < 4; ++r) rowof[r] = (int)dprobe_r[r] - 1;   // a-dim (= column here)
  const int rof = (int)dprobe_c[0] - 1;                          // b-dim (= our row), lane-const

  const int rowblk = blockIdx.x >> 1;              // 0..255
  const int split = blockIdx.x & 1;
  const long long row0 = (long long)rowblk * 64 + 16 * w;   // wave's 16-row base
  const int b = rowblk >> 5;                       // batch
  const int c0 = split * 1024;
  const double* Bb = normed + ((long long)b * NN + c0) * DD;

  // A-rows fragment (b-operand): lane holds row row0+c16, k in [32q,32q+32)
  double2 areg[16];
  {
    const double* Ap = normed + (row0 + c16) * DD + 32 * q;
    #pragma unroll
    for (int i = 0; i < 16; ++i) areg[i] = reinterpret_cast<const double2*>(Ap)[i];
  }

  u64 kv[8];
  #pragma unroll
  for (int s = 0; s < 8; ++s) kv[s] = 0ull;

  // B-cols fragments (a-operand), register double-buffered; same layout as areg
  double2 bregA[16], bregB[16];
  {
    const double* p = Bb + (long long)c16 * DD + 32 * q;   // tile 0
    #pragma unroll
    for (int i = 0; i < 16; ++i) bregA[i] = reinterpret_cast<const double2*>(p)[i];
  }

  for (int ct = 0; ct < NTILES; ct += 2) {
    // prefetch tile ct+1 into B (always valid: NTILES even)
    {
      const double* p = Bb + (long long)(16 * (ct + 1) + c16) * DD + 32 * q;
      #pragma unroll
      for (int i = 0; i < 16; ++i) bregB[i] = reinterpret_cast<const double2*>(p)[i];
    }
    // compute tile ct from A
    {
      d4 acc = {0.0, 0.0, 0.0, 0.0};
      #pragma unroll
      for (int s2 = 0; s2 < 16; ++s2) {
        acc = __builtin_amdgcn_mfma_f64_16x16x4f64(bregA[s2].x, areg[s2].x, acc, 0, 0, 0);
        acc = __builtin_amdgcn_mfma_f64_16x16x4f64(bregA[s2].y, areg[s2].y, acc, 0, 0, 0);
      }
      const int cb = c0 + 16 * ct;
      fold4(kv, make_key(acc[0], cb + rowof[0]), make_key(acc[1], cb + rowof[1]),
                make_key(acc[2], cb + rowof[2]), make_key(acc[3], cb + rowof[3]));
    }
    // prefetch tile ct+2 into A
    if (ct + 2 < NTILES) {
      const double* p = Bb + (long long)(16 * (ct + 2) + c16) * DD + 32 * q;
      #pragma unroll
      for (int i = 0; i < 16; ++i) bregA[i] = reinterpret_cast<const double2*>(p)[i];
    }
    // compute tile ct+1 from B
    {
      d4 acc = {0.0, 0.0, 0.0, 0.0};
      #pragma unroll
      for (int s2 = 0; s2 < 16; ++s2) {
        acc = __builtin_amdgcn_mfma_f64_16x16x4f64(bregB[s2].x, areg[s2].x, acc, 0, 0, 0);
        acc = __builtin_amdgcn_mfma_f64_16x16x4f64(bregB[s2].y, areg[s2].y, acc, 0, 0, 0);
      }
      const int cb = c0 + 16 * (ct + 1);
      fold4(kv, make_key(acc[0], cb + rowof[0]), make_key(acc[1], cb + rowof[1]),
                make_key(acc[2], cb + rowof[2]), make_key(acc[3], cb + rowof[3]));
    }
  }

  // merge the 4 lanes sharing each row (quads; same c16 -> same row)
  #pragma unroll
  for (int m = 16; m <= 32; m <<= 1) {
    u64 ov[8];
    #pragma unroll
    for (int s = 0; s < 8; ++s) ov[s] = __shfl_xor(kv[s], m, 64);
    merge8(kv, ov);
  }

  if (l < 16) {
    const long long base = ((long long)split * 16384 + row0 + rof) * 8;
    #pragma unroll
    for (int s = 0; s < 8; ++s) cand[base + s] = kv[s];
  }
}

// ---------------- K4: merge 2 splits per row, diag + symmetric scatter ----------------
__global__ __launch_bounds__(256) void k_merge(const u64* __restrict__ cand,
                                               float* __restrict__ out) {
  const long long r = (long long)blockIdx.x * 256 + threadIdx.x;  // 0..16383
  u64 kv[8], ov[8];
  #pragma unroll
  for (int s = 0; s < 8; ++s) kv[s] = cand[r * 8 + s];
  #pragma unroll
  for (int s = 0; s < 8; ++s) ov[s] = cand[(16384 + r) * 8 + s];
  merge8(kv, ov);
  const int n = (int)(r & (NN - 1));
  const long long bbase = (r - n) * (long long)NN;   // b*N*N
  out[r * (long long)NN + n] = 1.0f;                 // self loop (also in top-8, belt+suspenders)
  #pragma unroll
  for (int s = 0; s < 8; ++s) {
    const int m = 2047 - (int)(kv[s] & 2047ull);
    out[r * (long long)NN + m] = 1.0f;
    out[bbase + (long long)m * NN + n] = 1.0f;
  }
}

extern "C" void kernel_launch(void* const* d_in, const int* in_sizes, int n_in,
                              void* d_out, int out_size, void* d_ws, size_t ws_size,
                              hipStream_t stream) {
  const float* x = (const float*)d_in[0];
  float* out = (float*)d_out;
  char* ws = (char*)d_ws;
  double* normed = (double*)ws;                 // 16,777,216 B
  u64* cand = (u64*)(ws + 16777216);            //  2,097,152 B (2 x 16384 x 8 keys)

  hipMemsetAsync(d_out, 0, (size_t)out_size * sizeof(float), stream);
  hipLaunchKernelGGL(k_normalize, dim3(BATCH * NN / 4), dim3(256), 0, stream, x, normed);
  hipLaunchKernelGGL(k_scores_topk, dim3(512), dim3(256), 0, stream, normed, cand);
  hipLaunchKernelGGL(k_merge, dim3(64), dim3(256), 0, stream, cand, out);
}